// Round 13
// baseline (15484.738 us; speedup 1.0000x reference)
//
#include <hip/hip_runtime.h>

// LSTM S=512,B=64,I=256,H=512 (f32 buffers).
// R13: R12's XCD fast path never validated (blockIdx->XCD mapping is
// undefined; groups straddled XCDs -> stale L2 reads -> timeout+slow).
// Fix: RUNTIME ELECTION. Each WG reads HW_REG_XCC_ID (measured m09),
// atomicAdds a per-XCD counter, spins until all 64 WGs registered.
// If every XCD has exactly 8 WGs: dynamic roles bg=xcc, hg=slot -> each
// bg-group co-XCD BY CONSTRUCTION, sc0 (L2-resident) tagged exchange.
// Else: uniform static roles + pure L3 slow path (~R10/R11).
// Replay-safe: prep does NOT touch MBF; producers publish their own h0
// slice (tag 0) in the prologue through their own XCD's L2; tagged data
// + bit-deterministic replays make stale-line tag collisions harmless.
// Compute core = R12 (passed -> verified): N=8-in-16 16x16x32 MFMA tiles,
// static afr, k-major conflict-free LDS.

#define SS 512
#define BB 64
#define II 256
#define HH 512
#define GROW 2048
#define TBN  (SS*BB)
#define FAST_TRIES 4096

typedef unsigned int u32;
typedef unsigned short u16;
typedef unsigned long long u64;
typedef _Float16 __attribute__((ext_vector_type(8))) h16x8;
typedef __attribute__((ext_vector_type(2))) float f32x2;
typedef __attribute__((ext_vector_type(4))) float f32x4;
typedef __attribute__((ext_vector_type(16))) float f32x16;
typedef u32 __attribute__((ext_vector_type(4))) u32x4;
typedef u32 __attribute__((ext_vector_type(2))) u32x2;

// ---------------- XP-path ws layout ----------------
#define A2_DW   (8 * 8 * 2 * 16 * 256)        // 524288 dwords = 2 MB (h A-frags)
#define WXA_DW  (64 * 16 * 256)               // 262144 dwords = 1 MB (x A-frags)
#define XA2_OFF  0
#define XWXA_OFF ((size_t)A2_DW * 4)                    // 2,097,152
#define XBS_OFF  (XWXA_OFF + (size_t)WXA_DW * 4)        // 3,145,728 (bsum 8 KB)
#define XMBF_OFF (XBS_OFF + 8192)                       // 3,153,920 (fast mbox 256 KB)
#define XMBS_OFF (XMBF_OFF + 262144)                    // 3,416,064 (slow mbox 256 KB)
#define XEL_OFF  (XMBS_OFF + 262144)                    // 3,678,208 (elect 512 B)
#define XXP_OFF  ((size_t)4 * 1024 * 1024)              // 4,194,304
#define XP_BYTES ((size_t)GROW * TBN * 2)               // 134,217,728
#define WS_XP    (XXP_OFF + XP_BYTES)                   // 138,412,032

// ---------------- R5-fallback ws layout ----------------
#define A_DWORDS (32 * 2 * 2 * 24 * 64 * 4)           // 786432
#define HB_OFF   ((size_t)A_DWORDS * 4)               // 3,145,728
#define FL_OFF   (HB_OFF + 2 * (size_t)BB * HH * 2)   // +131,072
#define WS_NEED  (FL_OFF + 4096)

__device__ __forceinline__ u32 pk2h(float a, float b) {
    union { _Float16 h[2]; u32 u; } v;
    v.h[0] = (_Float16)a; v.h[1] = (_Float16)b; return v.u;
}
__device__ __forceinline__ u16 f2h(float a) {
    union { _Float16 h; u16 u; } v; v.h = (_Float16)a; return v.u;
}
__device__ __forceinline__ float h2f(u16 u) {
    union { u16 u; _Float16 h; } v; v.u = u; return (float)v.h;
}
__device__ __forceinline__ float sigf(float v)  { return 1.0f / (1.0f + __expf(-v)); }
__device__ __forceinline__ float tanhf_(float v){ return 1.0f - 2.0f / (1.0f + __expf(2.0f * v)); }

// L3-coherent (agent scope)
__device__ __forceinline__ void st_u32_coh(u32* p, u32 v) {
    __hip_atomic_store(p, v, __ATOMIC_RELAXED, __HIP_MEMORY_SCOPE_AGENT);
}
__device__ __forceinline__ void st_i32_coh(int* p, int v) {
    __hip_atomic_store(p, v, __ATOMIC_RELAXED, __HIP_MEMORY_SCOPE_AGENT);
}
__device__ __forceinline__ int ld_i32_coh(const int* p) {
    return __hip_atomic_load(p, __ATOMIC_RELAXED, __HIP_MEMORY_SCOPE_AGENT);
}
__device__ __forceinline__ u64 ld_u64_coh(const u64* p) {
    return __hip_atomic_load(p, __ATOMIC_RELAXED, __HIP_MEMORY_SCOPE_AGENT);
}

// L2-resident (sc0: bypass L1, stays in this XCD's L2)
__device__ __forceinline__ void st_u32_l2(u32* p, u32 v) {
    asm volatile("global_store_dword %0, %1, off sc0" :: "v"(p), "v"(v) : "memory");
}
__device__ __forceinline__ void ld4_u64_l2(const u64* p0, const u64* p1,
                                           const u64* p2, const u64* p3,
                                           u64& a, u64& b, u64& c, u64& d) {
    asm volatile(
        "global_load_dwordx2 %0, %4, off sc0\n\t"
        "global_load_dwordx2 %1, %5, off sc0\n\t"
        "global_load_dwordx2 %2, %6, off sc0\n\t"
        "global_load_dwordx2 %3, %7, off sc0\n\t"
        "s_waitcnt vmcnt(0)"
        : "=&v"(a), "=&v"(b), "=&v"(c), "=&v"(d)
        : "v"(p0), "v"(p1), "v"(p2), "v"(p3)
        : "memory");
}

// ===================================================================
// XP path
// ===================================================================

// A2 / WXA / bsum pack — unchanged from R10/R12 (verified).
__global__ __launch_bounds__(256) void xprep_pack(
    const float* __restrict__ Wfi, const float* __restrict__ Wfh,
    const float* __restrict__ Wii, const float* __restrict__ Wih,
    const float* __restrict__ Wci, const float* __restrict__ Wch,
    const float* __restrict__ Woi, const float* __restrict__ Woh,
    const float* __restrict__ bfi, const float* __restrict__ bfh,
    const float* __restrict__ bii, const float* __restrict__ bih,
    const float* __restrict__ bci, const float* __restrict__ bch,
    const float* __restrict__ boi, const float* __restrict__ boh,
    u32* __restrict__ A2, u32* __restrict__ WXA, float* __restrict__ bsum)
{
    int tid = blockIdx.x * 256 + threadIdx.x;
    if (tid < A2_DW) {
        int d = tid & 3, l = (tid >> 2) & 63, ks = (tid >> 8) & 15;
        int tile = (tid >> 12) & 1, mt = (tid >> 13) & 7, hg = tid >> 16;
        int row15 = l & 15;
        int ulocal = row15 >> 2, g = row15 & 3;
        int j = hg * 64 + mt * 8 + tile * 4 + ulocal;
        int k = ks * 32 + (l >> 4) * 8 + d * 2;
        const float* Wh = (g == 0) ? Wfh : (g == 1) ? Wih : (g == 2) ? Wch : Woh;
        A2[tid] = pk2h(Wh[j * HH + k], Wh[j * HH + k + 1]);
    } else if (tid < A2_DW + WXA_DW) {
        int t2 = tid - A2_DW;
        int d = t2 & 3, l = (t2 >> 2) & 63, kt = (t2 >> 8) & 15, gt = t2 >> 12;
        int r = l & 31, g = r & 3;
        int j = gt * 8 + (r >> 2);
        int k = kt * 16 + (l >> 5) * 8 + d * 2;
        const float* Wi = (g == 0) ? Wfi : (g == 1) ? Wii : (g == 2) ? Wci : Woi;
        WXA[t2] = pk2h(Wi[j * II + k], Wi[j * II + k + 1]);
    } else if (tid < A2_DW + WXA_DW + GROW) {
        int grow = tid - A2_DW - WXA_DW;
        int r = grow & 31, gt = grow >> 5;
        int g = r & 3, j = gt * 8 + (r >> 2);
        const float* bi = (g == 0) ? bfi : (g == 1) ? bii : (g == 2) ? bci : boi;
        const float* bh = (g == 0) ? bfh : (g == 1) ? bih : (g == 2) ? bch : boh;
        bsum[grow] = bi[j] + bh[j];
    }
}

// prep: MBS slot0 <- h0 tag0, slot1 <- guard tag 0xFFFF; zero election table.
// MBF is deliberately NOT touched here (avoid foreign-XCD dirty lines);
// producers publish their own h0 slice in the kernel prologue.
__global__ __launch_bounds__(256) void xprep_mbs(
    const float* __restrict__ h0, u32* __restrict__ MBS, int* __restrict__ elect)
{
    int tid = blockIdx.x * 256 + threadIdx.x;   // < 65536
    int slot = tid >> 15, rem = tid & 32767;
    int b = rem >> 9, j = rem & 511;
    u32 v = (slot == 0) ? (((u32)f2h(h0[b * HH + j])) << 16) : 0x0000FFFFu;
    st_u32_coh(MBS + tid, v);
    if (tid < 8) st_i32_coh(&elect[tid * 16], 0);
}

// xproj: XPq[(j*512 + t)*64 + b] = u64 of 4 f16 gates — unchanged (verified).
__global__ __launch_bounds__(512, 1) void xproj(
    const float* __restrict__ x, const u32* __restrict__ WXA,
    const float* __restrict__ bsum, u64* __restrict__ XPq)
{
    const int wgid = blockIdx.x;
    const int tid = threadIdx.x, lane = tid & 63, w = tid >> 6;
    const int TB0 = wgid * 128;
    __shared__ __align__(16) u32 XB[32 * 128 * 4];

    #pragma unroll
    for (int it = 0; it < 16; ++it) {
        int c = it * 512 + tid;
        int m = c >> 6, ck = c & 63;
        f32x4 v = *(const f32x4*)(x + (size_t)(TB0 + m) * II + ck * 4);
        u32x2 p; p.x = pk2h(v.x, v.y); p.y = pk2h(v.z, v.w);
        *(u32x2*)(XB + ((ck >> 1) * 128 + m) * 4 + (ck & 1) * 2) = p;
    }
    __syncthreads();

    const int gtw = w & 3, nh = w >> 2;
    const int khi = lane >> 5;
    for (int nt = 0; nt < 2; ++nt) {
        const int col = nh * 64 + nt * 32 + (lane & 31);
        const int tb = TB0 + col;
        const int t_ = tb >> 6, b_ = tb & 63;
        h16x8 bfr[16];
        #pragma unroll
        for (int kt = 0; kt < 16; ++kt)
            bfr[kt] = *(const h16x8*)(XB + ((kt * 2 + khi) * 128 + col) * 4);
        for (int gti = 0; gti < 16; ++gti) {
            const int gt = gtw * 16 + gti;
            f32x16 acc;
            #pragma unroll
            for (int rg = 0; rg < 16; ++rg)
                acc[rg] = bsum[gt * 32 + (rg & 3) + 8 * (rg >> 2) + 4 * khi];
            const u32* ap = WXA + (size_t)(gt * 16) * 256 + lane * 4;
            #pragma unroll
            for (int kt = 0; kt < 16; ++kt) {
                h16x8 af = *(const h16x8*)(ap + kt * 256);
                acc = __builtin_amdgcn_mfma_f32_32x32x16_f16(af, bfr[kt], acc, 0, 0, 0);
            }
            #pragma unroll
            for (int q = 0; q < 4; ++q) {
                int j = gt * 8 + 2 * q + khi;
                union { u16 s[4]; u64 u; } pk;
                pk.s[0] = f2h(acc[4 * q + 0]);
                pk.s[1] = f2h(acc[4 * q + 1]);
                pk.s[2] = f2h(acc[4 * q + 2]);
                pk.s[3] = f2h(acc[4 * q + 3]);
                XPq[((size_t)j * 512 + t_) * 64 + b_] = pk.u;
            }
        }
    }
}

// recurrent: election-based roles; XCD-local L2 exchange when co-located.
__global__ __launch_bounds__(512, 1) void lstm_rec(
    const float* __restrict__ h0, const float* __restrict__ c0,
    const u32* __restrict__ A2, u32* __restrict__ MBF, u32* __restrict__ MBS,
    int* __restrict__ elect, const u64* __restrict__ XPq, float* __restrict__ out)
{
    const int tid = threadIdx.x, lane = tid & 63, mt = tid >> 6;
    const int col = lane & 15;         // MFMA column (batches at col 0..7)
    const int kq  = lane >> 4;         // k-quarter / ulocal (0..3)

    __shared__ __align__(16) u16 HL[64 * 16 * 8];     // 16 KB
    __shared__ __align__(16) u32 hst32[8 * 65];       // publish gather
    __shared__ int rsh;
    char* HLc = (char*)HL;

    // zero cols 8..15 once (keeps garbage out of unused B columns)
    for (int i = tid; i < 2048; i += 512) {
        int r = i >> 5, rem = i & 31, c = 8 + (rem >> 2), q = rem & 3;
        *(u32*)(HLc + (r * 16 + c) * 16 + q * 4) = 0;
    }

    // --- election: are the 64 WGs evenly spread 8-per-XCD? ---
    if (tid == 0) {
        u32 xcc;
        asm volatile("s_getreg_b32 %0, hwreg(HW_REG_XCC_ID)" : "=s"(xcc));
        xcc &= 7;
        int slot = __hip_atomic_fetch_add(&elect[xcc * 16], 1,
                                          __ATOMIC_RELAXED, __HIP_MEMORY_SCOPE_AGENT);
        int total;
        do {
            total = 0;
            #pragma unroll
            for (int i = 0; i < 8; ++i) total += ld_i32_coh(&elect[i * 16]);
        } while (total < 64);
        bool ok = (slot < 8);
        #pragma unroll
        for (int i = 0; i < 8; ++i) ok = ok && (ld_i32_coh(&elect[i * 16]) == 8);
        rsh = ok ? (int)(0x40000000 | (xcc) | (slot << 3)) : 0;
    }
    __syncthreads();
    const int enc = rsh;
    const bool fastok = enc != 0;
    const int bg = fastok ? (enc & 7) : (int)(blockIdx.x & 7);
    const int hg = fastok ? ((enc >> 3) & 7) : (int)(blockIdx.x >> 3);
    bool slowmode = !fastok;

    const int bc = (col < 8) ? col : 7;
    const int b  = bg * 8 + bc;        // clamped global batch for loads

    // A fragments, STATIC indices (hg only shifts the base pointer)
    h16x8 afr0[16], afr1[16];
    {
        const u32* a0 = A2 + ((size_t)((hg * 8 + mt) * 2 + 0) * 16) * 256 + lane * 4;
        const u32* a1 = A2 + ((size_t)((hg * 8 + mt) * 2 + 1) * 16) * 256 + lane * 4;
        #pragma unroll
        for (int ks = 0; ks < 16; ++ks) {
            afr0[ks] = *(const h16x8*)(a0 + ks * 256);
            afr1[ks] = *(const h16x8*)(a1 + ks * 256);
        }
    }

    const int j0 = hg * 64 + mt * 8 + kq;
    const int j1 = j0 + 4;

    float cst0 = c0[b * HH + j0];
    float cst1 = c0[b * HH + j1];

    // --- prologue: publish own h0 slice (tag 0) via own-XCD L2 + L3 ---
    {
        int br = tid >> 6, jl = tid & 63;
        int bb = bg * 8 + br, jj = hg * 64 + jl;
        u32 pv = ((u32)f2h(h0[bb * HH + jj]) << 16);
        size_t pidx = (size_t)bg * 4096 + br * 512 + hg * 64 + jl;  // slot 0
        st_u32_l2(MBF + pidx, pv);
        st_u32_coh(MBS + pidx, pv);
    }

    for (int t = 0; t < SS; ++t) {
        // XP prefetch (plain cached loads, in flight under the poll)
        u64 xq0 = XPq[((size_t)j0 * SS + t) * BB + b];
        u64 xq1 = XPq[((size_t)j1 * SS + t) * BB + b];

        // --- poll + ingest: 4 u64 (8 tagged u32), validate, retry ---
        const size_t g64 = (size_t)(t & 1) * 16384 + bg * 2048;   // u64 index
        const u64* f64 = (const u64*)MBF + g64;
        const u64* s64 = (const u64*)MBS + g64;
        const u32 tg = (u32)t & 0xFFFFu;
        u64 v0, v1, v2, v3;
        int tries = 0;
        for (;;) {
            if (!slowmode) {
                ld4_u64_l2(f64 + tid, f64 + 512 + tid, f64 + 1024 + tid, f64 + 1536 + tid,
                           v0, v1, v2, v3);
            } else {
                v0 = ld_u64_coh(s64 + tid);
                v1 = ld_u64_coh(s64 + 512 + tid);
                v2 = ld_u64_coh(s64 + 1024 + tid);
                v3 = ld_u64_coh(s64 + 1536 + tid);
            }
            bool ok = ((u32)v0 & 0xFFFFu) == tg && ((u32)(v0 >> 32) & 0xFFFFu) == tg
                   && ((u32)v1 & 0xFFFFu) == tg && ((u32)(v1 >> 32) & 0xFFFFu) == tg
                   && ((u32)v2 & 0xFFFFu) == tg && ((u32)(v2 >> 32) & 0xFFFFu) == tg
                   && ((u32)v3 & 0xFFFFu) == tg && ((u32)(v3 >> 32) & 0xFFFFu) == tg;
            if (ok) break;
            if (!slowmode && ++tries > FAST_TRIES) slowmode = true;
        }

        // extract payloads -> k-major swizzled LDS (cols 0..7)
        #pragma unroll
        for (int i = 0; i < 4; ++i) {
            u64 v = (i == 0) ? v0 : (i == 1) ? v1 : (i == 2) ? v2 : v3;
            int idx = i * 512 + tid;             // u64 index in group slice
            int br = idx >> 8, jp = idx & 255;   // [b 8][jp 256]
            int k8 = jp >> 2, q = jp & 3;
            u32 lo = (u32)v, hi = (u32)(v >> 32);
            u32 pk = (lo >> 16) | (hi & 0xFFFF0000u);
            *(u32*)(HLc + (k8 * 16 + (br ^ (k8 & 7))) * 16 + q * 4) = pk;
        }
        __syncthreads();

        // K-loop: 16 wave-linear ds_read_b128 + 32 MFMAs 16x16x32
        f32x4 acc0 = {0.f, 0.f, 0.f, 0.f}, acc1 = {0.f, 0.f, 0.f, 0.f};
        #pragma unroll
        for (int ks = 0; ks < 16; ++ks) {
            const int k8 = ks * 4 + kq;
            h16x8 bf = *(const h16x8*)(HLc + (k8 * 16 + (col ^ (k8 & 7))) * 16);
            acc0 = __builtin_amdgcn_mfma_f32_16x16x32_f16(afr0[ks], bf, acc0, 0, 0, 0);
            acc1 = __builtin_amdgcn_mfma_f32_16x16x32_f16(afr1[ks], bf, acc1, 0, 0, 0);
        }

        // in-register pointwise (acc reg index == gate)
        float hv0, hv1;
        {
            union { u64 u; u16 s[4]; } xu; xu.u = xq0;
            float af = acc0[0] + h2f(xu.s[0]);
            float ai = acc0[1] + h2f(xu.s[1]);
            float ac = acc0[2] + h2f(xu.s[2]);
            float ao = acc0[3] + h2f(xu.s[3]);
            float cn = cst0 * sigf(af) + sigf(ai) * tanhf_(ac);
            cst0 = cn; hv0 = sigf(ao) * tanhf_(cn);
        }
        {
            union { u64 u; u16 s[4]; } xu; xu.u = xq1;
            float af = acc1[0] + h2f(xu.s[0]);
            float ai = acc1[1] + h2f(xu.s[1]);
            float ac = acc1[2] + h2f(xu.s[2]);
            float ao = acc1[3] + h2f(xu.s[3]);
            float cn = cst1 * sigf(af) + sigf(ai) * tanhf_(ac);
            cst1 = cn; hv1 = sigf(ao) * tanhf_(cn);
        }

        // tagged h words -> LDS staging (real batches only)
        const u32 tagn = (u32)(t + 1) & 0xFFFFu;
        if (col < 8) {
            hst32[col * 65 + (mt * 8 + kq)]     = ((u32)f2h(hv0) << 16) | tagn;
            hst32[col * 65 + (mt * 8 + 4 + kq)] = ((u32)f2h(hv1) << 16) | tagn;
        }
        __syncthreads();

        // publisher: thread -> one (b, jl); fast (own-XCD L2) + slow (L3) + out
        {
            const int br = tid >> 6, jl = tid & 63;
            u32 pv = hst32[br * 65 + jl];
            if (t < SS - 1) {
                size_t pidx = (size_t)((t + 1) & 1) * 32768 + bg * 4096
                            + br * 512 + hg * 64 + jl;
                st_u32_l2(MBF + pidx, pv);
                st_u32_coh(MBS + pidx, pv);
            }
            float ho = h2f((u16)(pv >> 16));
            out[((size_t)t * BB + bg * 8 + br) * HH + hg * 64 + jl] = ho;
            if (t == SS - 1) {
                out[(size_t)SS * BB * HH + (size_t)(bg * 8 + br) * HH + hg * 64 + jl] = ho;
            }
        }
        if (t == SS - 1 && col < 8) {
            out[(size_t)SS * BB * HH + BB * HH + b * HH + j0] = cst0;
            out[(size_t)SS * BB * HH + BB * HH + b * HH + j1] = cst1;
        }
    }
}

// ===================================================================
// R5 fallback path (proven 2.63 ms) — verbatim
// ===================================================================
__global__ __launch_bounds__(256) void prep_A(
    const float* __restrict__ Wfi, const float* __restrict__ Wfh,
    const float* __restrict__ Wii, const float* __restrict__ Wih,
    const float* __restrict__ Wci, const float* __restrict__ Wch,
    const float* __restrict__ Woi, const float* __restrict__ Woh,
    u32* __restrict__ A)
{
    int tid = blockIdx.x * 256 + threadIdx.x;
    int wg = tid / 24576;  int r = tid - wg * 24576;
    int mt = r / 12288;    r -= mt * 12288;
    int ks = r / 6144;     r -= ks * 6144;
    int kt = r / 256;      r -= kt * 256;
    int l  = r >> 2;       int d = r & 3;

    int row = mt * 32 + (l & 31);
    int g   = row >> 4;
    int j   = wg * 16 + (row & 15);
    int k   = ks * 384 + kt * 16 + (l >> 5) * 8 + d * 2;

    const float* Wi = (g == 0) ? Wfi : (g == 1) ? Wii : (g == 2) ? Wci : Woi;
    const float* Wh = (g == 0) ? Wfh : (g == 1) ? Wih : (g == 2) ? Wch : Woh;
    float w0, w1;
    if (k < II) { w0 = Wi[j * II + k];        w1 = Wi[j * II + k + 1]; }
    else        { int kk = k - II; w0 = Wh[j * HH + kk]; w1 = Wh[j * HH + kk + 1]; }
    A[tid] = pk2h(w0, w1);
}

__global__ __launch_bounds__(256) void prep_misc(
    const float* __restrict__ h0, u16* __restrict__ hb, int* __restrict__ flags)
{
    int tid = blockIdx.x * 256 + threadIdx.x;
    if (tid < BB * HH) {
        int b = tid >> 9, j = tid & 511;
        hb[(j >> 3) * 512 + b * 8 + (j & 7)] = f2h(h0[tid]);
    }
    if (tid < 32) flags[tid * 32] = 0;
}

__global__ __launch_bounds__(512, 1) void lstm_mfma(
    const float* __restrict__ x,  const float* __restrict__ c0,
    const float* __restrict__ bfi, const float* __restrict__ bfh,
    const float* __restrict__ bii, const float* __restrict__ bih,
    const float* __restrict__ bci, const float* __restrict__ bch,
    const float* __restrict__ boi, const float* __restrict__ boh,
    const u32* __restrict__ A, u16* __restrict__ hb, int* __restrict__ flags,
    float* __restrict__ out)
{
    const int wg   = blockIdx.x;
    const int tid  = threadIdx.x;
    const int lane = tid & 63;
    const int w    = tid >> 6;
    const int mt   = w & 1;
    const int nt2  = (w >> 1) & 1;
    const int ks   = w >> 2;
    const int khi  = lane >> 5;
    const int nb   = nt2 * 32 + (lane & 31);

    __shared__ __align__(16) u16 BS[8192 * 8];
    char* BSc = (char*)BS;

    h16x8 afr[24];
    {
        const u32* ab = A + ((wg * 2 + mt) * 2 + ks) * (24 * 256) + lane * 4;
        #pragma unroll
        for (int kt = 0; kt < 24; ++kt)
            afr[kt] = *(const h16x8*)(ab + kt * 256);
    }

    f32x16 acc_init;
    #pragma unroll
    for (int rg = 0; rg < 16; ++rg) {
        int row = mt * 32 + (rg & 3) + 8 * (rg >> 2) + 4 * khi;
        float bv = 0.0f;
        if (ks == 0) {
            int g = row >> 4, j = wg * 16 + (row & 15);
            const float* bi = (g == 0) ? bfi : (g == 1) ? bii : (g == 2) ? bci : boi;
            const float* bh = (g == 0) ? bfh : (g == 1) ? bih : (g == 2) ? bch : boh;
            bv = bi[j] + bh[j];
        }
        acc_init[rg] = bv;
    }

    const int bown = tid & 63;
    const int w8   = tid >> 6;
    const int j0   = wg * 16 + 2 * w8;
    float cst[2];
    {
        const f32x2 cv = *(const f32x2*)(c0 + bown * HH + j0);
        cst[0] = cv.x; cst[1] = cv.y;
    }

    #pragma unroll
    for (int i = 0; i < 4; ++i) {
        int cid = i * 512 + tid;
        int bq = cid >> 5, k8 = cid & 31;
        const f32x4* sp = (const f32x4*)(x + bq * II + k8 * 8);
        f32x4 v0 = sp[0], v1 = sp[1];
        u32x4 pk;
        pk.x = pk2h(v0[0], v0[1]); pk.y = pk2h(v0[2], v0[3]);
        pk.z = pk2h(v1[0], v1[1]); pk.w = pk2h(v1[2], v1[3]);
        *(u32x4*)&BSc[(k8 * 64 + (bq ^ (k8 & 7))) * 16] = pk;
    }

    for (int t = 0; t < SS; ++t) {
        const int cur = t & 1;
        float* GLp = (float*)(BSc + (size_t)(cur ^ 1) * 2048 * 16);

        {
            const u16* hsrc = hb + cur * (BB * HH);
            u64 hr[16];
            #pragma unroll
            for (int it = 0; it < 8; ++it) {
                int cd = it * 512 + tid;
                int k8h = cd >> 6, bpos = cd & 63;
                int bq = bpos ^ (k8h & 7);
                const u64* p = (const u64*)(hsrc + k8h * 512 + bq * 8);
                hr[2 * it]     = ld_u64_coh(p);
                hr[2 * it + 1] = ld_u64_coh(p + 1);
            }
            #pragma unroll
            for (int it = 0; it < 8; ++it) {
                int cd = it * 512 + tid;
                union { u64 q[2]; u32x4 v; } u;
                u.q[0] = hr[2 * it]; u.q[1] = hr[2 * it + 1];
                *(u32x4*)&BSc[(4096 + cd) * 16] = u.v;
            }
        }

        f32x4 xv[8];
        if (t + 1 < SS) {
            const float* xt = x + (size_t)(t + 1) * BB * II;
            #pragma unroll
            for (int i = 0; i < 4; ++i) {
                int cid = i * 512 + tid;
                int bq = cid >> 5, k8 = cid & 31;
                const f32x4* sp = (const f32x4*)(xt + bq * II + k8 * 8);
                xv[2 * i] = sp[0]; xv[2 * i + 1] = sp[1];
            }
        }

        __syncthreads();

        f32x16 acc = acc_init;
        #pragma unroll
        for (int kt = 0; kt < 24; ++kt) {
            int k8g = ks * 48 + kt * 2 + khi;
            int off;
            if (k8g < 32) { int q = k8g & 7;
                off = (cur * 2048 + k8g * 64 + ((nb ^ q))) * 16;
            } else {        int k8h = k8g - 32; int q = k8h & 7;
                off = (4096 + k8h * 64 + ((nb ^ q))) * 16;
            }
            h16x8 bf = *(const h16x8*)(BSc + off);
            acc = __builtin_amdgcn_mfma_f32_32x32x16_f16(afr[kt], bf, acc, 0, 0, 0);
        }

        #pragma unroll
        for (int rg = 0; rg < 16; ++rg) {
            int row = mt * 32 + (rg & 3) + 8 * (rg >> 2) + 4 * khi;
            GLp[ks * 4096 + row * 64 + nb] = acc[rg];
        }
        __syncthreads();

        float hv2[2];
        #pragma unroll
        for (int i = 0; i < 2; ++i) {
            int m = 2 * w8 + i;
            float af = GLp[(0 * 16 + m) * 64 + bown] + GLp[4096 + (0 * 16 + m) * 64 + bown];
            float ai = GLp[(1 * 16 + m) * 64 + bown] + GLp[4096 + (1 * 16 + m) * 64 + bown];
            float ac = GLp[(2 * 16 + m) * 64 + bown] + GLp[4096 + (2 * 16 + m) * 64 + bown];
            float ao = GLp[(3 * 16 + m) * 64 + bown] + GLp[4096 + (3 * 16 + m) * 64 + bown];
            float fg = sigf(af), ig = sigf(ai), cg = tanhf_(ac), og = sigf(ao);
            float cn = cst[i] * fg + ig * cg;
            cst[i] = cn;
            hv2[i] = og * tanhf_(cn);
        }
        {
            f32x2 ho; ho.x = hv2[0]; ho.y = hv2[1];
            *(f32x2*)(out + ((size_t)t * BB + bown) * HH + j0) = ho;
        }
        st_u32_coh((u32*)(hb + ((t + 1) & 1) * (BB * HH) + (j0 >> 3) * 512 + bown * 8 + (j0 & 7)),
                   pk2h(hv2[0], hv2[1]));

        if (t == SS - 1) {
            f32x2 ho; ho.x = hv2[0]; ho.y = hv2[1];
            f32x2 co; co.x = cst[0]; co.y = cst[1];
            *(f32x2*)(out + (size_t)SS * BB * HH + bown * HH + j0) = ho;
            *(f32x2*)(out + (size_t)SS * BB * HH + BB * HH + bown * HH + j0) = co;
            break;
        }

        __syncthreads();
        if (tid == 0) st_i32_coh(&flags[wg * 32], t + 1);

        #pragma unroll
        for (int i = 0; i < 4; ++i) {
            int cid = i * 512 + tid;
            int bq = cid >> 5, k8 = cid & 31;
            f32x4 v0 = xv[2 * i], v1 = xv[2 * i + 1];
            u32x4 pk;
            pk.x = pk2h(v0[0], v0[1]); pk.y = pk2h(v0[2], v0[3]);
            pk.z = pk2h(v1[0], v1[1]); pk.w = pk2h(v1[2], v1[3]);
            *(u32x4*)&BSc[((cur ^ 1) * 2048 + k8 * 64 + (bq ^ (k8 & 7))) * 16] = pk;
        }

        if (tid < 32) {
            while (ld_i32_coh(&flags[tid * 32]) < t + 1) {}
        }
        asm volatile("" ::: "memory");
        __syncthreads();
    }
}

extern "C" void kernel_launch(void* const* d_in, const int* in_sizes, int n_in,
                              void* d_out, int out_size, void* d_ws, size_t ws_size,
                              hipStream_t stream) {
    const float* x   = (const float*)d_in[0];
    const float* h0  = (const float*)d_in[1];
    const float* c0  = (const float*)d_in[2];
    const float* Wfi = (const float*)d_in[3];
    const float* bfi = (const float*)d_in[4];
    const float* Wfh = (const float*)d_in[5];
    const float* bfh = (const float*)d_in[6];
    const float* Wii = (const float*)d_in[7];
    const float* bii = (const float*)d_in[8];
    const float* Wih = (const float*)d_in[9];
    const float* bih = (const float*)d_in[10];
    const float* Wci = (const float*)d_in[11];
    const float* bci = (const float*)d_in[12];
    const float* Wch = (const float*)d_in[13];
    const float* bch = (const float*)d_in[14];
    const float* Woi = (const float*)d_in[15];
    const float* boi = (const float*)d_in[16];
    const float* Woh = (const float*)d_in[17];
    const float* boh = (const float*)d_in[18];

    if (ws_size >= WS_XP) {
        u32*   A2   = (u32*)((char*)d_ws + XA2_OFF);
        u32*   WXA  = (u32*)((char*)d_ws + XWXA_OFF);
        float* bsum = (float*)((char*)d_ws + XBS_OFF);
        u32*   MBF  = (u32*)((char*)d_ws + XMBF_OFF);
        u32*   MBS  = (u32*)((char*)d_ws + XMBS_OFF);
        int*   elc  = (int*)((char*)d_ws + XEL_OFF);
        u64*   XPq  = (u64*)((char*)d_ws + XXP_OFF);

        xprep_pack<<<dim3((A2_DW + WXA_DW + GROW + 255) / 256), dim3(256), 0, stream>>>(
            Wfi, Wfh, Wii, Wih, Wci, Wch, Woi, Woh,
            bfi, bfh, bii, bih, bci, bch, boi, boh, A2, WXA, bsum);
        xprep_mbs<<<dim3(256), dim3(256), 0, stream>>>(h0, MBS, elc);
        xproj<<<dim3(TBN / 128), dim3(512), 0, stream>>>(x, WXA, bsum, XPq);
        lstm_rec<<<dim3(64), dim3(512), 0, stream>>>(h0, c0, A2, MBF, MBS, elc, XPq, (float*)d_out);
    } else {
        u32* A     = (u32*)d_ws;
        u16* hbb   = (u16*)((char*)d_ws + HB_OFF);
        int* flags = (int*)((char*)d_ws + FL_OFF);
        prep_A<<<dim3(A_DWORDS / 256), dim3(256), 0, stream>>>(
            Wfi, Wfh, Wii, Wih, Wci, Wch, Woi, Woh, A);
        prep_misc<<<dim3(128), dim3(256), 0, stream>>>(h0, hbb, flags);
        lstm_mfma<<<dim3(32), dim3(512), 0, stream>>>(
            x, c0, bfi, bfh, bii, bih, bci, bch, boi, boh,
            A, hbb, flags, (float*)d_out);
    }
}

// Round 14
// 12873.264 us; speedup vs baseline: 1.2029x; 1.2029x over previous
//
#include <hip/hip_runtime.h>

// LSTM S=512,B=64,I=256,H=512 (f32 buffers).
// R14: R10/R11 floor = serialized wait-ALL -> load-ALL -> compute-ALL chain
// (~2.5us/step). R12/R13 XCD-L2 detours regressed (placement/coherence
// unreliable) - abandoned. This round: BARRIER-FREE per-lane pipeline.
// Mailbox [slot][b][j] of tagged u32 (f16<<16|tag16, R11-verified format).
// Each lane loads exactly its own MFMA B-frag words per producer chunk
// (16 tagged u32), validates tags itself, MFMAs - no LDS, no syncthreads
// in the whole step. Fixed literal chunk order 0..7 (static afr), depth-4
// register pipeline (issue 0-3; process p / issue p+4) overlaps detect
// latency. Publish: per-lane fire-and-forget tagged stores (no drain/flag).
// Skew-safe: every wave reads every (b,j) of its bg-group each step.

#define SS 512
#define BB 64
#define II 256
#define HH 512
#define GROW 2048
#define TBN  (SS*BB)

typedef unsigned int u32;
typedef unsigned short u16;
typedef unsigned long long u64;
typedef _Float16 __attribute__((ext_vector_type(8))) h16x8;
typedef __attribute__((ext_vector_type(2))) float f32x2;
typedef __attribute__((ext_vector_type(4))) float f32x4;
typedef __attribute__((ext_vector_type(16))) float f32x16;
typedef u32 __attribute__((ext_vector_type(4))) u32x4;
typedef u32 __attribute__((ext_vector_type(2))) u32x2;

// ---------------- XP-path ws layout ----------------
#define A2_DW   (8 * 8 * 2 * 16 * 256)        // 524288 dwords = 2 MB (h A-frags)
#define WXA_DW  (64 * 16 * 256)               // 262144 dwords = 1 MB (x A-frags)
#define XA2_OFF  0
#define XWXA_OFF ((size_t)A2_DW * 4)                    // 2,097,152
#define XBS_OFF  (XWXA_OFF + (size_t)WXA_DW * 4)        // 3,145,728 (bsum 8 KB)
#define XMB_OFF  (XBS_OFF + 8192)                       // 3,153,920 (mailbox 256 KB)
#define XXP_OFF  ((size_t)4 * 1024 * 1024)              // 4,194,304
#define XP_BYTES ((size_t)GROW * TBN * 2)               // 134,217,728
#define WS_XP    (XXP_OFF + XP_BYTES)                   // 138,412,032

// ---------------- R5-fallback ws layout ----------------
#define A_DWORDS (32 * 2 * 2 * 24 * 64 * 4)           // 786432
#define HB_OFF   ((size_t)A_DWORDS * 4)               // 3,145,728
#define FL_OFF   (HB_OFF + 2 * (size_t)BB * HH * 2)   // +131,072
#define WS_NEED  (FL_OFF + 4096)

__device__ __forceinline__ u32 pk2h(float a, float b) {
    union { _Float16 h[2]; u32 u; } v;
    v.h[0] = (_Float16)a; v.h[1] = (_Float16)b; return v.u;
}
__device__ __forceinline__ u16 f2h(float a) {
    union { _Float16 h; u16 u; } v; v.h = (_Float16)a; return v.u;
}
__device__ __forceinline__ float h2f(u16 u) {
    union { u16 u; _Float16 h; } v; v.u = u; return (float)v.h;
}
__device__ __forceinline__ float sigf(float v)  { return 1.0f / (1.0f + __expf(-v)); }
__device__ __forceinline__ float tanhf_(float v){ return 1.0f - 2.0f / (1.0f + __expf(2.0f * v)); }

// L3-coherent (agent scope) relaxed atomics
__device__ __forceinline__ void st_u32_coh(u32* p, u32 v) {
    __hip_atomic_store(p, v, __ATOMIC_RELAXED, __HIP_MEMORY_SCOPE_AGENT);
}
__device__ __forceinline__ void st_i32_coh(int* p, int v) {
    __hip_atomic_store(p, v, __ATOMIC_RELAXED, __HIP_MEMORY_SCOPE_AGENT);
}
__device__ __forceinline__ int ld_i32_coh(const int* p) {
    return __hip_atomic_load(p, __ATOMIC_RELAXED, __HIP_MEMORY_SCOPE_AGENT);
}
__device__ __forceinline__ u64 ld_u64_coh(const u64* p) {
    return __hip_atomic_load(p, __ATOMIC_RELAXED, __HIP_MEMORY_SCOPE_AGENT);
}

// ===================================================================
// XP path
// ===================================================================

// A2 / WXA / bsum pack — unchanged from R10 (verified).
__global__ __launch_bounds__(256) void xprep_pack(
    const float* __restrict__ Wfi, const float* __restrict__ Wfh,
    const float* __restrict__ Wii, const float* __restrict__ Wih,
    const float* __restrict__ Wci, const float* __restrict__ Wch,
    const float* __restrict__ Woi, const float* __restrict__ Woh,
    const float* __restrict__ bfi, const float* __restrict__ bfh,
    const float* __restrict__ bii, const float* __restrict__ bih,
    const float* __restrict__ bci, const float* __restrict__ bch,
    const float* __restrict__ boi, const float* __restrict__ boh,
    u32* __restrict__ A2, u32* __restrict__ WXA, float* __restrict__ bsum)
{
    int tid = blockIdx.x * 256 + threadIdx.x;
    if (tid < A2_DW) {
        int d = tid & 3, l = (tid >> 2) & 63, ks = (tid >> 8) & 15;
        int tile = (tid >> 12) & 1, mt = (tid >> 13) & 7, hg = tid >> 16;
        int row15 = l & 15;
        int ulocal = row15 >> 2, g = row15 & 3;
        int j = hg * 64 + mt * 8 + tile * 4 + ulocal;
        int k = ks * 32 + (l >> 4) * 8 + d * 2;
        const float* Wh = (g == 0) ? Wfh : (g == 1) ? Wih : (g == 2) ? Wch : Woh;
        A2[tid] = pk2h(Wh[j * HH + k], Wh[j * HH + k + 1]);
    } else if (tid < A2_DW + WXA_DW) {
        int t2 = tid - A2_DW;
        int d = t2 & 3, l = (t2 >> 2) & 63, kt = (t2 >> 8) & 15, gt = t2 >> 12;
        int r = l & 31, g = r & 3;
        int j = gt * 8 + (r >> 2);
        int k = kt * 16 + (l >> 5) * 8 + d * 2;
        const float* Wi = (g == 0) ? Wfi : (g == 1) ? Wii : (g == 2) ? Wci : Woi;
        WXA[t2] = pk2h(Wi[j * II + k], Wi[j * II + k + 1]);
    } else if (tid < A2_DW + WXA_DW + GROW) {
        int grow = tid - A2_DW - WXA_DW;
        int r = grow & 31, gt = grow >> 5;
        int g = r & 3, j = gt * 8 + (r >> 2);
        const float* bi = (g == 0) ? bfi : (g == 1) ? bii : (g == 2) ? bci : boi;
        const float* bh = (g == 0) ? bfh : (g == 1) ? bih : (g == 2) ? bch : boh;
        bsum[grow] = bi[j] + bh[j];
    }
}

// Mailbox MB[slot 2][b 64][j 512] tagged u32 (u32 = f16<<16 | tag16).
// slot0 <- h0 tag 0; slot1 <- guard tag 0xFFFF. Covers ALL entries (replay-safe).
__global__ __launch_bounds__(256) void xprep_mb(
    const float* __restrict__ h0, u32* __restrict__ MB)
{
    int tid = blockIdx.x * 256 + threadIdx.x;   // < 65536
    int slot = tid >> 15, rem = tid & 32767;
    int b = rem >> 9, j = rem & 511;
    u32 v = (slot == 0) ? (((u32)f2h(h0[b * HH + j])) << 16) : 0x0000FFFFu;
    st_u32_coh(MB + tid, v);
}

// xproj: XPq[(j*512 + t)*64 + b] = u64 of 4 f16 gates — unchanged (verified).
__global__ __launch_bounds__(512, 1) void xproj(
    const float* __restrict__ x, const u32* __restrict__ WXA,
    const float* __restrict__ bsum, u64* __restrict__ XPq)
{
    const int wgid = blockIdx.x;
    const int tid = threadIdx.x, lane = tid & 63, w = tid >> 6;
    const int TB0 = wgid * 128;
    __shared__ __align__(16) u32 XB[32 * 128 * 4];

    #pragma unroll
    for (int it = 0; it < 16; ++it) {
        int c = it * 512 + tid;
        int m = c >> 6, ck = c & 63;
        f32x4 v = *(const f32x4*)(x + (size_t)(TB0 + m) * II + ck * 4);
        u32x2 p; p.x = pk2h(v.x, v.y); p.y = pk2h(v.z, v.w);
        *(u32x2*)(XB + ((ck >> 1) * 128 + m) * 4 + (ck & 1) * 2) = p;
    }
    __syncthreads();

    const int gtw = w & 3, nh = w >> 2;
    const int khi = lane >> 5;
    for (int nt = 0; nt < 2; ++nt) {
        const int col = nh * 64 + nt * 32 + (lane & 31);
        const int tb = TB0 + col;
        const int t_ = tb >> 6, b_ = tb & 63;
        h16x8 bfr[16];
        #pragma unroll
        for (int kt = 0; kt < 16; ++kt)
            bfr[kt] = *(const h16x8*)(XB + ((kt * 2 + khi) * 128 + col) * 4);
        for (int gti = 0; gti < 16; ++gti) {
            const int gt = gtw * 16 + gti;
            f32x16 acc;
            #pragma unroll
            for (int rg = 0; rg < 16; ++rg)
                acc[rg] = bsum[gt * 32 + (rg & 3) + 8 * (rg >> 2) + 4 * khi];
            const u32* ap = WXA + (size_t)(gt * 16) * 256 + lane * 4;
            #pragma unroll
            for (int kt = 0; kt < 16; ++kt) {
                h16x8 af = *(const h16x8*)(ap + kt * 256);
                acc = __builtin_amdgcn_mfma_f32_32x32x16_f16(af, bfr[kt], acc, 0, 0, 0);
            }
            #pragma unroll
            for (int q = 0; q < 4; ++q) {
                int j = gt * 8 + 2 * q + khi;
                union { u16 s[4]; u64 u; } pk;
                pk.s[0] = f2h(acc[4 * q + 0]);
                pk.s[1] = f2h(acc[4 * q + 1]);
                pk.s[2] = f2h(acc[4 * q + 2]);
                pk.s[3] = f2h(acc[4 * q + 3]);
                XPq[((size_t)j * 512 + t_) * 64 + b_] = pk.u;
            }
        }
    }
}

// recurrent: barrier-free per-lane tagged pipeline. 32 WGs (8 hg x 4 bg).
__global__ __launch_bounds__(512, 1) void lstm_rec(
    const float* __restrict__ c0,
    const u32* __restrict__ A2, u32* __restrict__ MB,
    const u64* __restrict__ XPq, float* __restrict__ out)
{
    const int wg = blockIdx.x;
    const int hg = wg >> 2, bg = wg & 3;
    const int tid = threadIdx.x, lane = tid & 63, mt = tid >> 6;
    const int col = lane & 15;         // batch-local (MFMA col)
    const int kq  = lane >> 4;         // k-quarter (0..3)
    const int b   = bg * 16 + col;     // global batch

    // A fragments, STATIC indices: 2 tiles x 16 ks x 4 VGPR = 128
    h16x8 afr0[16], afr1[16];
    {
        const u32* a0 = A2 + ((size_t)((hg * 8 + mt) * 2 + 0) * 16) * 256 + lane * 4;
        const u32* a1 = A2 + ((size_t)((hg * 8 + mt) * 2 + 1) * 16) * 256 + lane * 4;
        #pragma unroll
        for (int ks = 0; ks < 16; ++ks) {
            afr0[ks] = *(const h16x8*)(a0 + ks * 256);
            afr1[ks] = *(const h16x8*)(a1 + ks * 256);
        }
    }

    const int j0 = hg * 64 + mt * 8 + kq;      // tile-0 unit (lane owns 4 gates)
    const int j1 = j0 + 4;                     // tile-1 unit

    float cst0 = c0[b * HH + j0];
    float cst1 = c0[b * HH + j1];

    // per-lane chunk-load base (u64 units): slot + b*256 + p*32 + kq*4
    const int lbase = b * 256 + kq * 4;

    for (int t = 0; t < SS; ++t) {
        // XP prefetch (issued first; consumed at pointwise)
        u64 xq0 = XPq[((size_t)j0 * SS + t) * BB + b];
        u64 xq1 = XPq[((size_t)j1 * SS + t) * BB + b];

        const u64* S = (const u64*)MB + (size_t)(t & 1) * 16384;
        const u32 tg = (u32)t & 0xFFFFu;

        f32x4 acc0 = {0.f, 0.f, 0.f, 0.f}, acc1 = {0.f, 0.f, 0.f, 0.f};
        u64 st[4][8];

        // issue 8 u64 loads for chunk P into stage slot Sl
        #define ISSUE(P, Sl) { \
            const u64* q_ = S + (lbase + (P) * 32); \
            st[Sl][0] = ld_u64_coh(q_ + 0);  st[Sl][1] = ld_u64_coh(q_ + 1); \
            st[Sl][2] = ld_u64_coh(q_ + 2);  st[Sl][3] = ld_u64_coh(q_ + 3); \
            st[Sl][4] = ld_u64_coh(q_ + 16); st[Sl][5] = ld_u64_coh(q_ + 17); \
            st[Sl][6] = ld_u64_coh(q_ + 18); st[Sl][7] = ld_u64_coh(q_ + 19); }

        // validate tags of stage slot Sl; retry chunk P until wave-all valid;
        // then unpack 2 B-frags and do 4 MFMAs (chunk P covers ks=2P, 2P+1)
        #define PROC(P, Sl) { \
            for (;;) { \
                bool ok_ = true; \
                _Pragma("unroll") \
                for (int i_ = 0; i_ < 8; ++i_) { \
                    u32 lo_ = (u32)st[Sl][i_], hi_ = (u32)(st[Sl][i_] >> 32); \
                    ok_ = ok_ && ((lo_ & 0xFFFFu) == tg) && ((hi_ & 0xFFFFu) == tg); \
                } \
                if (__all(ok_)) break; \
                ISSUE(P, Sl); \
            } \
            union { u32x4 u; h16x8 h; } b0_, b1_; \
            _Pragma("unroll") \
            for (int i_ = 0; i_ < 4; ++i_) { \
                u32 lo_ = (u32)st[Sl][i_], hi_ = (u32)(st[Sl][i_] >> 32); \
                b0_.u[i_] = (lo_ >> 16) | (hi_ & 0xFFFF0000u); \
                u32 lo2_ = (u32)st[Sl][4 + i_], hi2_ = (u32)(st[Sl][4 + i_] >> 32); \
                b1_.u[i_] = (lo2_ >> 16) | (hi2_ & 0xFFFF0000u); \
            } \
            acc0 = __builtin_amdgcn_mfma_f32_16x16x32_f16(afr0[2*(P)],   b0_.h, acc0, 0, 0, 0); \
            acc0 = __builtin_amdgcn_mfma_f32_16x16x32_f16(afr0[2*(P)+1], b1_.h, acc0, 0, 0, 0); \
            acc1 = __builtin_amdgcn_mfma_f32_16x16x32_f16(afr1[2*(P)],   b0_.h, acc1, 0, 0, 0); \
            acc1 = __builtin_amdgcn_mfma_f32_16x16x32_f16(afr1[2*(P)+1], b1_.h, acc1, 0, 0, 0); }

        ISSUE(0, 0); ISSUE(1, 1); ISSUE(2, 2); ISSUE(3, 3);
        PROC(0, 0);  ISSUE(4, 0);
        PROC(1, 1);  ISSUE(5, 1);
        PROC(2, 2);  ISSUE(6, 2);
        PROC(3, 3);  ISSUE(7, 3);
        PROC(4, 0);
        PROC(5, 1);
        PROC(6, 2);
        PROC(7, 3);

        #undef ISSUE
        #undef PROC

        // in-register pointwise (acc reg index == gate)
        float hv0, hv1;
        {
            union { u64 u; u16 s[4]; } xu; xu.u = xq0;
            float af = acc0[0] + h2f(xu.s[0]);
            float ai = acc0[1] + h2f(xu.s[1]);
            float ac = acc0[2] + h2f(xu.s[2]);
            float ao = acc0[3] + h2f(xu.s[3]);
            float cn = cst0 * sigf(af) + sigf(ai) * tanhf_(ac);
            cst0 = cn; hv0 = sigf(ao) * tanhf_(cn);
        }
        {
            union { u64 u; u16 s[4]; } xu; xu.u = xq1;
            float af = acc1[0] + h2f(xu.s[0]);
            float ai = acc1[1] + h2f(xu.s[1]);
            float ac = acc1[2] + h2f(xu.s[2]);
            float ao = acc1[3] + h2f(xu.s[3]);
            float cn = cst1 * sigf(af) + sigf(ai) * tanhf_(ac);
            cst1 = cn; hv1 = sigf(ao) * tanhf_(cn);
        }

        // publish: fire-and-forget tagged stores (no drain, no flag)
        if (t < SS - 1) {
            u32* D = MB + (size_t)((t + 1) & 1) * 32768;
            const u32 tagn = (u32)(t + 1) & 0xFFFFu;
            st_u32_coh(D + b * 512 + j0, ((u32)f2h(hv0) << 16) | tagn);
            st_u32_coh(D + b * 512 + j1, ((u32)f2h(hv1) << 16) | tagn);
        }

        // out stores (off the critical path)
        out[((size_t)t * BB + b) * HH + j0] = hv0;
        out[((size_t)t * BB + b) * HH + j1] = hv1;
        if (t == SS - 1) {
            out[(size_t)SS * BB * HH + b * HH + j0] = hv0;
            out[(size_t)SS * BB * HH + b * HH + j1] = hv1;
            out[(size_t)SS * BB * HH + BB * HH + b * HH + j0] = cst0;
            out[(size_t)SS * BB * HH + BB * HH + b * HH + j1] = cst1;
        }
    }
}

// ===================================================================
// R5 fallback path (proven 2.63 ms) — verbatim
// ===================================================================
__global__ __launch_bounds__(256) void prep_A(
    const float* __restrict__ Wfi, const float* __restrict__ Wfh,
    const float* __restrict__ Wii, const float* __restrict__ Wih,
    const float* __restrict__ Wci, const float* __restrict__ Wch,
    const float* __restrict__ Woi, const float* __restrict__ Woh,
    u32* __restrict__ A)
{
    int tid = blockIdx.x * 256 + threadIdx.x;
    int wg = tid / 24576;  int r = tid - wg * 24576;
    int mt = r / 12288;    r -= mt * 12288;
    int ks = r / 6144;     r -= ks * 6144;
    int kt = r / 256;      r -= kt * 256;
    int l  = r >> 2;       int d = r & 3;

    int row = mt * 32 + (l & 31);
    int g   = row >> 4;
    int j   = wg * 16 + (row & 15);
    int k   = ks * 384 + kt * 16 + (l >> 5) * 8 + d * 2;

    const float* Wi = (g == 0) ? Wfi : (g == 1) ? Wii : (g == 2) ? Wci : Woi;
    const float* Wh = (g == 0) ? Wfh : (g == 1) ? Wih : (g == 2) ? Wch : Woh;
    float w0, w1;
    if (k < II) { w0 = Wi[j * II + k];        w1 = Wi[j * II + k + 1]; }
    else        { int kk = k - II; w0 = Wh[j * HH + kk]; w1 = Wh[j * HH + kk + 1]; }
    A[tid] = pk2h(w0, w1);
}

__global__ __launch_bounds__(256) void prep_misc(
    const float* __restrict__ h0, u16* __restrict__ hb, int* __restrict__ flags)
{
    int tid = blockIdx.x * 256 + threadIdx.x;
    if (tid < BB * HH) {
        int b = tid >> 9, j = tid & 511;
        hb[(j >> 3) * 512 + b * 8 + (j & 7)] = f2h(h0[tid]);
    }
    if (tid < 32) flags[tid * 32] = 0;
}

__global__ __launch_bounds__(512, 1) void lstm_mfma(
    const float* __restrict__ x,  const float* __restrict__ c0,
    const float* __restrict__ bfi, const float* __restrict__ bfh,
    const float* __restrict__ bii, const float* __restrict__ bih,
    const float* __restrict__ bci, const float* __restrict__ bch,
    const float* __restrict__ boi, const float* __restrict__ boh,
    const u32* __restrict__ A, u16* __restrict__ hb, int* __restrict__ flags,
    float* __restrict__ out)
{
    const int wg   = blockIdx.x;
    const int tid  = threadIdx.x;
    const int lane = tid & 63;
    const int w    = tid >> 6;
    const int mt   = w & 1;
    const int nt2  = (w >> 1) & 1;
    const int ks   = w >> 2;
    const int khi  = lane >> 5;
    const int nb   = nt2 * 32 + (lane & 31);

    __shared__ __align__(16) u16 BS[8192 * 8];
    char* BSc = (char*)BS;

    h16x8 afr[24];
    {
        const u32* ab = A + ((wg * 2 + mt) * 2 + ks) * (24 * 256) + lane * 4;
        #pragma unroll
        for (int kt = 0; kt < 24; ++kt)
            afr[kt] = *(const h16x8*)(ab + kt * 256);
    }

    f32x16 acc_init;
    #pragma unroll
    for (int rg = 0; rg < 16; ++rg) {
        int row = mt * 32 + (rg & 3) + 8 * (rg >> 2) + 4 * khi;
        float bv = 0.0f;
        if (ks == 0) {
            int g = row >> 4, j = wg * 16 + (row & 15);
            const float* bi = (g == 0) ? bfi : (g == 1) ? bii : (g == 2) ? bci : boi;
            const float* bh = (g == 0) ? bfh : (g == 1) ? bih : (g == 2) ? bch : boh;
            bv = bi[j] + bh[j];
        }
        acc_init[rg] = bv;
    }

    const int bown = tid & 63;
    const int w8   = tid >> 6;
    const int j0   = wg * 16 + 2 * w8;
    float cst[2];
    {
        const f32x2 cv = *(const f32x2*)(c0 + bown * HH + j0);
        cst[0] = cv.x; cst[1] = cv.y;
    }

    #pragma unroll
    for (int i = 0; i < 4; ++i) {
        int cid = i * 512 + tid;
        int bq = cid >> 5, k8 = cid & 31;
        const f32x4* sp = (const f32x4*)(x + bq * II + k8 * 8);
        f32x4 v0 = sp[0], v1 = sp[1];
        u32x4 pk;
        pk.x = pk2h(v0[0], v0[1]); pk.y = pk2h(v0[2], v0[3]);
        pk.z = pk2h(v1[0], v1[1]); pk.w = pk2h(v1[2], v1[3]);
        *(u32x4*)&BSc[(k8 * 64 + (bq ^ (k8 & 7))) * 16] = pk;
    }

    for (int t = 0; t < SS; ++t) {
        const int cur = t & 1;
        float* GLp = (float*)(BSc + (size_t)(cur ^ 1) * 2048 * 16);

        {
            const u16* hsrc = hb + cur * (BB * HH);
            u64 hr[16];
            #pragma unroll
            for (int it = 0; it < 8; ++it) {
                int cd = it * 512 + tid;
                int k8h = cd >> 6, bpos = cd & 63;
                int bq = bpos ^ (k8h & 7);
                const u64* p = (const u64*)(hsrc + k8h * 512 + bq * 8);
                hr[2 * it]     = ld_u64_coh(p);
                hr[2 * it + 1] = ld_u64_coh(p + 1);
            }
            #pragma unroll
            for (int it = 0; it < 8; ++it) {
                int cd = it * 512 + tid;
                union { u64 q[2]; u32x4 v; } u;
                u.q[0] = hr[2 * it]; u.q[1] = hr[2 * it + 1];
                *(u32x4*)&BSc[(4096 + cd) * 16] = u.v;
            }
        }

        f32x4 xv[8];
        if (t + 1 < SS) {
            const float* xt = x + (size_t)(t + 1) * BB * II;
            #pragma unroll
            for (int i = 0; i < 4; ++i) {
                int cid = i * 512 + tid;
                int bq = cid >> 5, k8 = cid & 31;
                const f32x4* sp = (const f32x4*)(xt + bq * II + k8 * 8);
                xv[2 * i] = sp[0]; xv[2 * i + 1] = sp[1];
            }
        }

        __syncthreads();

        f32x16 acc = acc_init;
        #pragma unroll
        for (int kt = 0; kt < 24; ++kt) {
            int k8g = ks * 48 + kt * 2 + khi;
            int off;
            if (k8g < 32) { int q = k8g & 7;
                off = (cur * 2048 + k8g * 64 + ((nb ^ q))) * 16;
            } else {        int k8h = k8g - 32; int q = k8h & 7;
                off = (4096 + k8h * 64 + ((nb ^ q))) * 16;
            }
            h16x8 bf = *(const h16x8*)(BSc + off);
            acc = __builtin_amdgcn_mfma_f32_32x32x16_f16(afr[kt], bf, acc, 0, 0, 0);
        }

        #pragma unroll
        for (int rg = 0; rg < 16; ++rg) {
            int row = mt * 32 + (rg & 3) + 8 * (rg >> 2) + 4 * khi;
            GLp[ks * 4096 + row * 64 + nb] = acc[rg];
        }
        __syncthreads();

        float hv2[2];
        #pragma unroll
        for (int i = 0; i < 2; ++i) {
            int m = 2 * w8 + i;
            float af = GLp[(0 * 16 + m) * 64 + bown] + GLp[4096 + (0 * 16 + m) * 64 + bown];
            float ai = GLp[(1 * 16 + m) * 64 + bown] + GLp[4096 + (1 * 16 + m) * 64 + bown];
            float ac = GLp[(2 * 16 + m) * 64 + bown] + GLp[4096 + (2 * 16 + m) * 64 + bown];
            float ao = GLp[(3 * 16 + m) * 64 + bown] + GLp[4096 + (3 * 16 + m) * 64 + bown];
            float fg = sigf(af), ig = sigf(ai), cg = tanhf_(ac), og = sigf(ao);
            float cn = cst[i] * fg + ig * cg;
            cst[i] = cn;
            hv2[i] = og * tanhf_(cn);
        }
        {
            f32x2 ho; ho.x = hv2[0]; ho.y = hv2[1];
            *(f32x2*)(out + ((size_t)t * BB + bown) * HH + j0) = ho;
        }
        st_u32_coh((u32*)(hb + ((t + 1) & 1) * (BB * HH) + (j0 >> 3) * 512 + bown * 8 + (j0 & 7)),
                   pk2h(hv2[0], hv2[1]));

        if (t == SS - 1) {
            f32x2 ho; ho.x = hv2[0]; ho.y = hv2[1];
            f32x2 co; co.x = cst[0]; co.y = cst[1];
            *(f32x2*)(out + (size_t)SS * BB * HH + bown * HH + j0) = ho;
            *(f32x2*)(out + (size_t)SS * BB * HH + BB * HH + bown * HH + j0) = co;
            break;
        }

        __syncthreads();
        if (tid == 0) st_i32_coh(&flags[wg * 32], t + 1);

        #pragma unroll
        for (int i = 0; i < 4; ++i) {
            int cid = i * 512 + tid;
            int bq = cid >> 5, k8 = cid & 31;
            f32x4 v0 = xv[2 * i], v1 = xv[2 * i + 1];
            u32x4 pk;
            pk.x = pk2h(v0[0], v0[1]); pk.y = pk2h(v0[2], v0[3]);
            pk.z = pk2h(v1[0], v1[1]); pk.w = pk2h(v1[2], v1[3]);
            *(u32x4*)&BSc[((cur ^ 1) * 2048 + k8 * 64 + (bq ^ (k8 & 7))) * 16] = pk;
        }

        if (tid < 32) {
            while (ld_i32_coh(&flags[tid * 32]) < t + 1) {}
        }
        asm volatile("" ::: "memory");
        __syncthreads();
    }
}

extern "C" void kernel_launch(void* const* d_in, const int* in_sizes, int n_in,
                              void* d_out, int out_size, void* d_ws, size_t ws_size,
                              hipStream_t stream) {
    const float* x   = (const float*)d_in[0];
    const float* h0  = (const float*)d_in[1];
    const float* c0  = (const float*)d_in[2];
    const float* Wfi = (const float*)d_in[3];
    const float* bfi = (const float*)d_in[4];
    const float* Wfh = (const float*)d_in[5];
    const float* bfh = (const float*)d_in[6];
    const float* Wii = (const float*)d_in[7];
    const float* bii = (const float*)d_in[8];
    const float* Wih = (const float*)d_in[9];
    const float* bih = (const float*)d_in[10];
    const float* Wci = (const float*)d_in[11];
    const float* bci = (const float*)d_in[12];
    const float* Wch = (const float*)d_in[13];
    const float* bch = (const float*)d_in[14];
    const float* Woi = (const float*)d_in[15];
    const float* boi = (const float*)d_in[16];
    const float* Woh = (const float*)d_in[17];
    const float* boh = (const float*)d_in[18];

    if (ws_size >= WS_XP) {
        u32*   A2   = (u32*)((char*)d_ws + XA2_OFF);
        u32*   WXA  = (u32*)((char*)d_ws + XWXA_OFF);
        float* bsum = (float*)((char*)d_ws + XBS_OFF);
        u32*   MB   = (u32*)((char*)d_ws + XMB_OFF);
        u64*   XPq  = (u64*)((char*)d_ws + XXP_OFF);

        xprep_pack<<<dim3((A2_DW + WXA_DW + GROW + 255) / 256), dim3(256), 0, stream>>>(
            Wfi, Wfh, Wii, Wih, Wci, Wch, Woi, Woh,
            bfi, bfh, bii, bih, bci, bch, boi, boh, A2, WXA, bsum);
        xprep_mb<<<dim3(256), dim3(256), 0, stream>>>(h0, MB);
        xproj<<<dim3(TBN / 128), dim3(512), 0, stream>>>(x, WXA, bsum, XPq);
        lstm_rec<<<dim3(32), dim3(512), 0, stream>>>(c0, A2, MB, XPq, (float*)d_out);
    } else {
        u32* A     = (u32*)d_ws;
        u16* hbb   = (u16*)((char*)d_ws + HB_OFF);
        int* flags = (int*)((char*)d_ws + FL_OFF);
        prep_A<<<dim3(A_DWORDS / 256), dim3(256), 0, stream>>>(
            Wfi, Wfh, Wii, Wih, Wci, Wch, Woi, Woh, A);
        prep_misc<<<dim3(128), dim3(256), 0, stream>>>(h0, hbb, flags);
        lstm_mfma<<<dim3(32), dim3(512), 0, stream>>>(
            x, c0, bfi, bfh, bii, bih, bci, bch, boi, boh,
            A, hbb, flags, (float*)d_out);
    }
}

// Round 15
// 1397.380 us; speedup vs baseline: 11.0813x; 9.2124x over previous
//
#include <hip/hip_runtime.h>

// LSTM S=512,B=64,I=256,H=512 (f32 buffers).
// FINAL (= R10, session best 1.399 ms): x-projection hoisted out of the
// recurrence (XPq precomputed chip-wide); recurrent loop = h-GEMM only.
// 32 WGs = 8 hidden-groups x 4 batch-groups; h exchanged within each
// 4-batch-group (8 WGs) via L3-coherent mailbox, fence-free relaxed
// agent-scope protocol (flag publish after implicit vmcnt(0) drain).
// k-major conflict-free LDS; 16x16x32 MFMA with static A-fragment regs;
// in-register pointwise (lane holds all 4 gates).
// Residual cost (measured R10-R14): ~2.5us/step of serialized cross-XCD
// L3 visibility latency - protocol variants (tagged/no-flag R11), XCD-L2
// fast paths (R12/R13), and barrier-free per-lane streams (R14) all
// regressed or tied; this is the structural floor for 512 sequential
// cross-chip dependencies at current primitives.

#define SS 512
#define BB 64
#define II 256
#define HH 512
#define NWG 32
#define GROW 2048
#define TBN  (SS*BB)

typedef unsigned int u32;
typedef unsigned short u16;
typedef unsigned long long u64;
typedef _Float16 __attribute__((ext_vector_type(8))) h16x8;
typedef __attribute__((ext_vector_type(2))) float f32x2;
typedef __attribute__((ext_vector_type(4))) float f32x4;
typedef __attribute__((ext_vector_type(16))) float f32x16;
typedef u32 __attribute__((ext_vector_type(4))) u32x4;
typedef u32 __attribute__((ext_vector_type(2))) u32x2;

// ---------------- XP-path ws layout ----------------
#define A2_DW   (8 * 8 * 2 * 16 * 256)        // 524288 dwords = 2 MB (h A-frags)
#define WXA_DW  (64 * 16 * 256)               // 262144 dwords = 1 MB (x A-frags)
#define XA2_OFF  0
#define XWXA_OFF ((size_t)A2_DW * 4)                    // 2,097,152
#define XBS_OFF  (XWXA_OFF + (size_t)WXA_DW * 4)        // 3,145,728 (bsum 8 KB)
#define XHB_OFF  (XBS_OFF + 8192)                       // 3,153,920 (hb 128 KB)
#define XFL_OFF  (XHB_OFF + 2 * (size_t)BB * HH * 2)    // 3,284,992 (flags 2 KB)
#define XXP_OFF  ((size_t)4 * 1024 * 1024)              // 4,194,304
#define XP_BYTES ((size_t)GROW * TBN * 2)               // 134,217,728
#define WS_XP    (XXP_OFF + XP_BYTES)                   // 138,412,032

// ---------------- R5-fallback ws layout ----------------
#define A_DWORDS (32 * 2 * 2 * 24 * 64 * 4)           // 786432
#define HB_OFF   ((size_t)A_DWORDS * 4)               // 3,145,728
#define FL_OFF   (HB_OFF + 2 * (size_t)BB * HH * 2)   // +131,072
#define WS_NEED  (FL_OFF + 4096)

__device__ __forceinline__ u32 pk2h(float a, float b) {
    union { _Float16 h[2]; u32 u; } v;
    v.h[0] = (_Float16)a; v.h[1] = (_Float16)b; return v.u;
}
__device__ __forceinline__ u16 f2h(float a) {
    union { _Float16 h; u16 u; } v; v.h = (_Float16)a; return v.u;
}
__device__ __forceinline__ float h2f(u16 u) {
    union { u16 u; _Float16 h; } v; v.u = u; return (float)v.h;
}
__device__ __forceinline__ float sigf(float v)  { return 1.0f / (1.0f + __expf(-v)); }
__device__ __forceinline__ float tanhf_(float v){ return 1.0f - 2.0f / (1.0f + __expf(2.0f * v)); }

// relaxed agent-scope (coherent-at-L3, no cache-maintenance fences)
__device__ __forceinline__ void st_u32_coh(u32* p, u32 v) {
    __hip_atomic_store(p, v, __ATOMIC_RELAXED, __HIP_MEMORY_SCOPE_AGENT);
}
__device__ __forceinline__ void st_u64_coh(u64* p, u64 v) {
    __hip_atomic_store(p, v, __ATOMIC_RELAXED, __HIP_MEMORY_SCOPE_AGENT);
}
__device__ __forceinline__ void st_i32_coh(int* p, int v) {
    __hip_atomic_store(p, v, __ATOMIC_RELAXED, __HIP_MEMORY_SCOPE_AGENT);
}
__device__ __forceinline__ int ld_i32_coh(const int* p) {
    return __hip_atomic_load(p, __ATOMIC_RELAXED, __HIP_MEMORY_SCOPE_AGENT);
}
__device__ __forceinline__ u64 ld_u64_coh(const u64* p) {
    return __hip_atomic_load(p, __ATOMIC_RELAXED, __HIP_MEMORY_SCOPE_AGENT);
}

// ===================================================================
// XP path
// ===================================================================

// A2: h-weight A-frags for mfma_f32_16x16x32_f16.
__global__ __launch_bounds__(256) void xprep_pack(
    const float* __restrict__ Wfi, const float* __restrict__ Wfh,
    const float* __restrict__ Wii, const float* __restrict__ Wih,
    const float* __restrict__ Wci, const float* __restrict__ Wch,
    const float* __restrict__ Woi, const float* __restrict__ Woh,
    const float* __restrict__ bfi, const float* __restrict__ bfh,
    const float* __restrict__ bii, const float* __restrict__ bih,
    const float* __restrict__ bci, const float* __restrict__ bch,
    const float* __restrict__ boi, const float* __restrict__ boh,
    u32* __restrict__ A2, u32* __restrict__ WXA, float* __restrict__ bsum)
{
    int tid = blockIdx.x * 256 + threadIdx.x;
    if (tid < A2_DW) {
        int d = tid & 3, l = (tid >> 2) & 63, ks = (tid >> 8) & 15;
        int tile = (tid >> 12) & 1, mt = (tid >> 13) & 7, hg = tid >> 16;
        int row15 = l & 15;
        int ulocal = row15 >> 2, g = row15 & 3;
        int j = hg * 64 + mt * 8 + tile * 4 + ulocal;
        int k = ks * 32 + (l >> 4) * 8 + d * 2;
        const float* Wh = (g == 0) ? Wfh : (g == 1) ? Wih : (g == 2) ? Wch : Woh;
        A2[tid] = pk2h(Wh[j * HH + k], Wh[j * HH + k + 1]);
    } else if (tid < A2_DW + WXA_DW) {
        int t2 = tid - A2_DW;
        int d = t2 & 3, l = (t2 >> 2) & 63, kt = (t2 >> 8) & 15, gt = t2 >> 12;
        int r = l & 31, g = r & 3;
        int j = gt * 8 + (r >> 2);
        int k = kt * 16 + (l >> 5) * 8 + d * 2;
        const float* Wi = (g == 0) ? Wfi : (g == 1) ? Wii : (g == 2) ? Wci : Woi;
        WXA[t2] = pk2h(Wi[j * II + k], Wi[j * II + k + 1]);
    } else if (tid < A2_DW + WXA_DW + GROW) {
        int grow = tid - A2_DW - WXA_DW;
        int r = grow & 31, gt = grow >> 5;
        int g = r & 3, j = gt * 8 + (r >> 2);
        const float* bi = (g == 0) ? bfi : (g == 1) ? bii : (g == 2) ? bci : boi;
        const float* bh = (g == 0) ? bfh : (g == 1) ? bih : (g == 2) ? bch : boh;
        bsum[grow] = bi[j] + bh[j];
    }
}

// hb layout: [buf 2][b 64][k 512] f16
__global__ __launch_bounds__(256) void xprep_hb(
    const float* __restrict__ h0, u16* __restrict__ hb, int* __restrict__ flags)
{
    int tid = blockIdx.x * 256 + threadIdx.x;   // < 32768
    if (tid < BB * HH) hb[tid] = f2h(h0[tid]);
    if (tid < NWG) flags[tid * 16] = 0;         // 64B-strided flags
}

// xproj: XPq[(j*512 + t)*64 + b] = u64 of 4 f16 gates {f,i,c,o} of unit j.
__global__ __launch_bounds__(512, 1) void xproj(
    const float* __restrict__ x, const u32* __restrict__ WXA,
    const float* __restrict__ bsum, u64* __restrict__ XPq)
{
    const int wgid = blockIdx.x;
    const int tid = threadIdx.x, lane = tid & 63, w = tid >> 6;
    const int TB0 = wgid * 128;
    __shared__ __align__(16) u32 XB[32 * 128 * 4];

    #pragma unroll
    for (int it = 0; it < 16; ++it) {
        int c = it * 512 + tid;
        int m = c >> 6, ck = c & 63;
        f32x4 v = *(const f32x4*)(x + (size_t)(TB0 + m) * II + ck * 4);
        u32x2 p; p.x = pk2h(v.x, v.y); p.y = pk2h(v.z, v.w);
        *(u32x2*)(XB + ((ck >> 1) * 128 + m) * 4 + (ck & 1) * 2) = p;
    }
    __syncthreads();

    const int gtw = w & 3, nh = w >> 2;
    const int khi = lane >> 5;
    for (int nt = 0; nt < 2; ++nt) {
        const int col = nh * 64 + nt * 32 + (lane & 31);
        const int tb = TB0 + col;
        const int t_ = tb >> 6, b_ = tb & 63;
        h16x8 bfr[16];
        #pragma unroll
        for (int kt = 0; kt < 16; ++kt)
            bfr[kt] = *(const h16x8*)(XB + ((kt * 2 + khi) * 128 + col) * 4);
        for (int gti = 0; gti < 16; ++gti) {
            const int gt = gtw * 16 + gti;
            f32x16 acc;
            #pragma unroll
            for (int rg = 0; rg < 16; ++rg)
                acc[rg] = bsum[gt * 32 + (rg & 3) + 8 * (rg >> 2) + 4 * khi];
            const u32* ap = WXA + (size_t)(gt * 16) * 256 + lane * 4;
            #pragma unroll
            for (int kt = 0; kt < 16; ++kt) {
                h16x8 af = *(const h16x8*)(ap + kt * 256);
                acc = __builtin_amdgcn_mfma_f32_32x32x16_f16(af, bfr[kt], acc, 0, 0, 0);
            }
            #pragma unroll
            for (int q = 0; q < 4; ++q) {
                int j = gt * 8 + 2 * q + khi;
                union { u16 s[4]; u64 u; } pk;
                pk.s[0] = f2h(acc[4 * q + 0]);
                pk.s[1] = f2h(acc[4 * q + 1]);
                pk.s[2] = f2h(acc[4 * q + 2]);
                pk.s[3] = f2h(acc[4 * q + 3]);
                XPq[((size_t)j * 512 + t_) * 64 + b_] = pk.u;
            }
        }
    }
}

// recurrent: 2-D split (8 hg x 4 bg), conflict-free k-major LDS.
__global__ __launch_bounds__(512, 2) void lstm_rec(
    const float* __restrict__ c0,
    const u32* __restrict__ A2, u16* __restrict__ hb, int* __restrict__ flags,
    const u64* __restrict__ XPq, float* __restrict__ out)
{
    const int wg = blockIdx.x;
    const int hg = wg >> 2, bg = wg & 3;
    const int tid = threadIdx.x, lane = tid & 63, mt = tid >> 6;
    const int bl = lane & 15;          // batch-local (MFMA col)
    const int kq = lane >> 4;          // k-quarter / ulocal (0..3)
    const int b  = bg * 16 + bl;       // global batch

    // HL16[k8 64][b^ 16] 16B entries, k-major: reads wave-linear (0-conflict),
    // transposing writes 4 accesses/bank = min phases (0-conflict).
    __shared__ __align__(16) u16 HL[64 * 16 * 8];   // 16 KB
    __shared__ __align__(16) u16 hst[16 * 64];      // 2 KB publish gather
    u64* hb64  = (u64*)hb;
    u64* hst64 = (u64*)hst;
    char* HLc  = (char*)HL;

    // A fragments, STATIC indices: 2 tiles x 16 ks x 4 VGPR = 128
    h16x8 afr0[16], afr1[16];
    {
        const u32* a0 = A2 + ((size_t)((hg * 8 + mt) * 2 + 0) * 16) * 256 + lane * 4;
        const u32* a1 = A2 + ((size_t)((hg * 8 + mt) * 2 + 1) * 16) * 256 + lane * 4;
        #pragma unroll
        for (int ks = 0; ks < 16; ++ks) {
            afr0[ks] = *(const h16x8*)(a0 + ks * 256);
            afr1[ks] = *(const h16x8*)(a1 + ks * 256);
        }
    }

    // units this lane owns (one per tile; all 4 gates in acc regs)
    const int j0 = hg * 64 + mt * 8 + kq;      // tile 0
    const int j1 = j0 + 4;                     // tile 1

    float cst0 = c0[b * HH + j0];
    float cst1 = c0[b * HH + j1];

    for (int t = 0; t < SS; ++t) {
        // XP prefetch (plain cached loads, before the spin)
        u64 xq0 = XPq[((size_t)j0 * SS + t) * BB + b];
        u64 xq1 = XPq[((size_t)j1 * SS + t) * BB + b];

        // spin: lane-parallel poll of the 8 producers of this bg-group
        if (tid < 8) { while (ld_i32_coh(&flags[(bg * 8 + tid) * 16]) < t) {} }
        asm volatile("" ::: "memory");
        __syncthreads();

        // ingest 16 KB slice -> k-major swizzled LDS (4 coalesced u64/thread)
        {
            const u64* src = hb64 + (size_t)(t & 1) * 8192 + bg * 2048;
            u64 v0 = ld_u64_coh(src + 0 * 512 + tid);
            u64 v1 = ld_u64_coh(src + 1 * 512 + tid);
            u64 v2 = ld_u64_coh(src + 2 * 512 + tid);
            u64 v3 = ld_u64_coh(src + 3 * 512 + tid);
            #pragma unroll
            for (int i = 0; i < 4; ++i) {
                u64 v = (i == 0) ? v0 : (i == 1) ? v1 : (i == 2) ? v2 : v3;
                int idx = i * 512 + tid;             // u64 index in slice
                int blr = idx >> 7, k4 = idx & 127;  // src: [b][k4]
                int k8 = k4 >> 1, half = k4 & 1;
                *(u64*)(HLc + (k8 * 16 + (blr ^ (k8 & 7))) * 16 + half * 8) = v;
            }
        }
        __syncthreads();

        // K-loop: 16 wave-linear ds_read_b128 + 32 MFMAs 16x16x32
        f32x4 acc0 = {0.f, 0.f, 0.f, 0.f}, acc1 = {0.f, 0.f, 0.f, 0.f};
        #pragma unroll
        for (int ks = 0; ks < 16; ++ks) {
            const int k8 = ks * 4 + kq;
            h16x8 bf = *(const h16x8*)(HLc + (k8 * 16 + (bl ^ (k8 & 7))) * 16);
            acc0 = __builtin_amdgcn_mfma_f32_16x16x32_f16(afr0[ks], bf, acc0, 0, 0, 0);
            acc1 = __builtin_amdgcn_mfma_f32_16x16x32_f16(afr1[ks], bf, acc1, 0, 0, 0);
        }

        // in-register pointwise (acc reg index == gate)
        float hv0, hv1;
        {
            union { u64 u; u16 s[4]; } xu; xu.u = xq0;
            float af = acc0[0] + h2f(xu.s[0]);
            float ai = acc0[1] + h2f(xu.s[1]);
            float ac = acc0[2] + h2f(xu.s[2]);
            float ao = acc0[3] + h2f(xu.s[3]);
            float cn = cst0 * sigf(af) + sigf(ai) * tanhf_(ac);
            cst0 = cn; hv0 = sigf(ao) * tanhf_(cn);
        }
        {
            union { u64 u; u16 s[4]; } xu; xu.u = xq1;
            float af = acc1[0] + h2f(xu.s[0]);
            float ai = acc1[1] + h2f(xu.s[1]);
            float ac = acc1[2] + h2f(xu.s[2]);
            float ao = acc1[3] + h2f(xu.s[3]);
            float cn = cst1 * sigf(af) + sigf(ai) * tanhf_(ac);
            cst1 = cn; hv1 = sigf(ao) * tanhf_(cn);
        }
        // hst swizzled (bits 3-5 of jl XOR bl&7): conflict-light u16 writes
        hst[bl * 64 + ((mt * 8 + kq)     ^ ((bl & 7) << 3))] = f2h(hv0);
        hst[bl * 64 + ((mt * 8 + 4 + kq) ^ ((bl & 7) << 3))] = f2h(hv1);

        if (t < SS - 1) {
            __syncthreads();   // hst complete
            if (tid < 256) {
                int blr = tid >> 4, ju = tid & 15;
                // inverse swizzle: u64 row idx = ((ju>>1)^(blr&7))*2 | (ju&1)
                int sj = ((((ju >> 1) ^ (blr & 7)) << 1) | (ju & 1));
                st_u64_coh(hb64 + (size_t)((t + 1) & 1) * 8192 + bg * 2048
                               + blr * 128 + hg * 16 + ju,
                           hst64[blr * 16 + sj]);
            }
            __syncthreads();   // vmcnt(0) drain -> stores visible at L3
            if (tid == 0) st_i32_coh(&flags[(bg * 8 + hg) * 16], t + 1);
        }

        // out stores after flag publish (drain hides in next step)
        out[((size_t)t * BB + b) * HH + j0] = hv0;
        out[((size_t)t * BB + b) * HH + j1] = hv1;
        if (t == SS - 1) {
            out[(size_t)SS * BB * HH + b * HH + j0] = hv0;
            out[(size_t)SS * BB * HH + b * HH + j1] = hv1;
            out[(size_t)SS * BB * HH + BB * HH + b * HH + j0] = cst0;
            out[(size_t)SS * BB * HH + BB * HH + b * HH + j1] = cst1;
        }
    }
}

// ===================================================================
// R5 fallback path (proven 2.63 ms) — verbatim
// ===================================================================
__global__ __launch_bounds__(256) void prep_A(
    const float* __restrict__ Wfi, const float* __restrict__ Wfh,
    const float* __restrict__ Wii, const float* __restrict__ Wih,
    const float* __restrict__ Wci, const float* __restrict__ Wch,
    const float* __restrict__ Woi, const float* __restrict__ Woh,
    u32* __restrict__ A)
{
    int tid = blockIdx.x * 256 + threadIdx.x;
    int wg = tid / 24576;  int r = tid - wg * 24576;
    int mt = r / 12288;    r -= mt * 12288;
    int ks = r / 6144;     r -= ks * 6144;
    int kt = r / 256;      r -= kt * 256;
    int l  = r >> 2;       int d = r & 3;

    int row = mt * 32 + (l & 31);
    int g   = row >> 4;
    int j   = wg * 16 + (row & 15);
    int k   = ks * 384 + kt * 16 + (l >> 5) * 8 + d * 2;

    const float* Wi = (g == 0) ? Wfi : (g == 1) ? Wii : (g == 2) ? Wci : Woi;
    const float* Wh = (g == 0) ? Wfh : (g == 1) ? Wih : (g == 2) ? Wch : Woh;
    float w0, w1;
    if (k < II) { w0 = Wi[j * II + k];        w1 = Wi[j * II + k + 1]; }
    else        { int kk = k - II; w0 = Wh[j * HH + kk]; w1 = Wh[j * HH + kk + 1]; }
    A[tid] = pk2h(w0, w1);
}

__global__ __launch_bounds__(256) void prep_misc(
    const float* __restrict__ h0, u16* __restrict__ hb, int* __restrict__ flags)
{
    int tid = blockIdx.x * 256 + threadIdx.x;
    if (tid < BB * HH) {
        int b = tid >> 9, j = tid & 511;
        hb[(j >> 3) * 512 + b * 8 + (j & 7)] = f2h(h0[tid]);
    }
    if (tid < 32) flags[tid * 32] = 0;
}

__global__ __launch_bounds__(512, 1) void lstm_mfma(
    const float* __restrict__ x,  const float* __restrict__ c0,
    const float* __restrict__ bfi, const float* __restrict__ bfh,
    const float* __restrict__ bii, const float* __restrict__ bih,
    const float* __restrict__ bci, const float* __restrict__ bch,
    const float* __restrict__ boi, const float* __restrict__ boh,
    const u32* __restrict__ A, u16* __restrict__ hb, int* __restrict__ flags,
    float* __restrict__ out)
{
    const int wg   = blockIdx.x;
    const int tid  = threadIdx.x;
    const int lane = tid & 63;
    const int w    = tid >> 6;
    const int mt   = w & 1;
    const int nt2  = (w >> 1) & 1;
    const int ks   = w >> 2;
    const int khi  = lane >> 5;
    const int nb   = nt2 * 32 + (lane & 31);

    __shared__ __align__(16) u16 BS[8192 * 8];
    char* BSc = (char*)BS;

    h16x8 afr[24];
    {
        const u32* ab = A + ((wg * 2 + mt) * 2 + ks) * (24 * 256) + lane * 4;
        #pragma unroll
        for (int kt = 0; kt < 24; ++kt)
            afr[kt] = *(const h16x8*)(ab + kt * 256);
    }

    f32x16 acc_init;
    #pragma unroll
    for (int rg = 0; rg < 16; ++rg) {
        int row = mt * 32 + (rg & 3) + 8 * (rg >> 2) + 4 * khi;
        float bv = 0.0f;
        if (ks == 0) {
            int g = row >> 4, j = wg * 16 + (row & 15);
            const float* bi = (g == 0) ? bfi : (g == 1) ? bii : (g == 2) ? bci : boi;
            const float* bh = (g == 0) ? bfh : (g == 1) ? bih : (g == 2) ? bch : boh;
            bv = bi[j] + bh[j];
        }
        acc_init[rg] = bv;
    }

    const int bown = tid & 63;
    const int w8   = tid >> 6;
    const int j0   = wg * 16 + 2 * w8;
    float cst[2];
    {
        const f32x2 cv = *(const f32x2*)(c0 + bown * HH + j0);
        cst[0] = cv.x; cst[1] = cv.y;
    }

    #pragma unroll
    for (int i = 0; i < 4; ++i) {
        int cid = i * 512 + tid;
        int bq = cid >> 5, k8 = cid & 31;
        const f32x4* sp = (const f32x4*)(x + bq * II + k8 * 8);
        f32x4 v0 = sp[0], v1 = sp[1];
        u32x4 pk;
        pk.x = pk2h(v0[0], v0[1]); pk.y = pk2h(v0[2], v0[3]);
        pk.z = pk2h(v1[0], v1[1]); pk.w = pk2h(v1[2], v1[3]);
        *(u32x4*)&BSc[(k8 * 64 + (bq ^ (k8 & 7))) * 16] = pk;
    }

    for (int t = 0; t < SS; ++t) {
        const int cur = t & 1;
        float* GLp = (float*)(BSc + (size_t)(cur ^ 1) * 2048 * 16);

        {
            const u16* hsrc = hb + cur * (BB * HH);
            u64 hr[16];
            #pragma unroll
            for (int it = 0; it < 8; ++it) {
                int cd = it * 512 + tid;
                int k8h = cd >> 6, bpos = cd & 63;
                int bq = bpos ^ (k8h & 7);
                const u64* p = (const u64*)(hsrc + k8h * 512 + bq * 8);
                hr[2 * it]     = ld_u64_coh(p);
                hr[2 * it + 1] = ld_u64_coh(p + 1);
            }
            #pragma unroll
            for (int it = 0; it < 8; ++it) {
                int cd = it * 512 + tid;
                union { u64 q[2]; u32x4 v; } u;
                u.q[0] = hr[2 * it]; u.q[1] = hr[2 * it + 1];
                *(u32x4*)&BSc[(4096 + cd) * 16] = u.v;
            }
        }

        f32x4 xv[8];
        if (t + 1 < SS) {
            const float* xt = x + (size_t)(t + 1) * BB * II;
            #pragma unroll
            for (int i = 0; i < 4; ++i) {
                int cid = i * 512 + tid;
                int bq = cid >> 5, k8 = cid & 31;
                const f32x4* sp = (const f32x4*)(xt + bq * II + k8 * 8);
                xv[2 * i] = sp[0]; xv[2 * i + 1] = sp[1];
            }
        }

        __syncthreads();

        f32x16 acc = acc_init;
        #pragma unroll
        for (int kt = 0; kt < 24; ++kt) {
            int k8g = ks * 48 + kt * 2 + khi;
            int off;
            if (k8g < 32) { int q = k8g & 7;
                off = (cur * 2048 + k8g * 64 + ((nb ^ q))) * 16;
            } else {        int k8h = k8g - 32; int q = k8h & 7;
                off = (4096 + k8h * 64 + ((nb ^ q))) * 16;
            }
            h16x8 bf = *(const h16x8*)(BSc + off);
            acc = __builtin_amdgcn_mfma_f32_32x32x16_f16(afr[kt], bf, acc, 0, 0, 0);
        }

        #pragma unroll
        for (int rg = 0; rg < 16; ++rg) {
            int row = mt * 32 + (rg & 3) + 8 * (rg >> 2) + 4 * khi;
            GLp[ks * 4096 + row * 64 + nb] = acc[rg];
        }
        __syncthreads();

        float hv2[2];
        #pragma unroll
        for (int i = 0; i < 2; ++i) {
            int m = 2 * w8 + i;
            float af = GLp[(0 * 16 + m) * 64 + bown] + GLp[4096 + (0 * 16 + m) * 64 + bown];
            float ai = GLp[(1 * 16 + m) * 64 + bown] + GLp[4096 + (1 * 16 + m) * 64 + bown];
            float ac = GLp[(2 * 16 + m) * 64 + bown] + GLp[4096 + (2 * 16 + m) * 64 + bown];
            float ao = GLp[(3 * 16 + m) * 64 + bown] + GLp[4096 + (3 * 16 + m) * 64 + bown];
            float fg = sigf(af), ig = sigf(ai), cg = tanhf_(ac), og = sigf(ao);
            float cn = cst[i] * fg + ig * cg;
            cst[i] = cn;
            hv2[i] = og * tanhf_(cn);
        }
        {
            f32x2 ho; ho.x = hv2[0]; ho.y = hv2[1];
            *(f32x2*)(out + ((size_t)t * BB + bown) * HH + j0) = ho;
        }
        st_u32_coh((u32*)(hb + ((t + 1) & 1) * (BB * HH) + (j0 >> 3) * 512 + bown * 8 + (j0 & 7)),
                   pk2h(hv2[0], hv2[1]));

        if (t == SS - 1) {
            f32x2 ho; ho.x = hv2[0]; ho.y = hv2[1];
            f32x2 co; co.x = cst[0]; co.y = cst[1];
            *(f32x2*)(out + (size_t)SS * BB * HH + bown * HH + j0) = ho;
            *(f32x2*)(out + (size_t)SS * BB * HH + BB * HH + bown * HH + j0) = co;
            break;
        }

        __syncthreads();
        if (tid == 0) st_i32_coh(&flags[wg * 32], t + 1);

        #pragma unroll
        for (int i = 0; i < 4; ++i) {
            int cid = i * 512 + tid;
            int bq = cid >> 5, k8 = cid & 31;
            f32x4 v0 = xv[2 * i], v1 = xv[2 * i + 1];
            u32x4 pk;
            pk.x = pk2h(v0[0], v0[1]); pk.y = pk2h(v0[2], v0[3]);
            pk.z = pk2h(v1[0], v1[1]); pk.w = pk2h(v1[2], v1[3]);
            *(u32x4*)&BSc[((cur ^ 1) * 2048 + k8 * 64 + (bq ^ (k8 & 7))) * 16] = pk;
        }

        if (tid < 32) {
            while (ld_i32_coh(&flags[tid * 32]) < t + 1) {}
        }
        asm volatile("" ::: "memory");
        __syncthreads();
    }
}

extern "C" void kernel_launch(void* const* d_in, const int* in_sizes, int n_in,
                              void* d_out, int out_size, void* d_ws, size_t ws_size,
                              hipStream_t stream) {
    const float* x   = (const float*)d_in[0];
    const float* h0  = (const float*)d_in[1];
    const float* c0  = (const float*)d_in[2];
    const float* Wfi = (const float*)d_in[3];
    const float* bfi = (const float*)d_in[4];
    const float* Wfh = (const float*)d_in[5];
    const float* bfh = (const float*)d_in[6];
    const float* Wii = (const float*)d_in[7];
    const float* bii = (const float*)d_in[8];
    const float* Wih = (const float*)d_in[9];
    const float* bih = (const float*)d_in[10];
    const float* Wci = (const float*)d_in[11];
    const float* bci = (const float*)d_in[12];
    const float* Wch = (const float*)d_in[13];
    const float* bch = (const float*)d_in[14];
    const float* Woi = (const float*)d_in[15];
    const float* boi = (const float*)d_in[16];
    const float* Woh = (const float*)d_in[17];
    const float* boh = (const float*)d_in[18];

    if (ws_size >= WS_XP) {
        u32*   A2   = (u32*)((char*)d_ws + XA2_OFF);
        u32*   WXA  = (u32*)((char*)d_ws + XWXA_OFF);
        float* bsum = (float*)((char*)d_ws + XBS_OFF);
        u16*   hbb  = (u16*)((char*)d_ws + XHB_OFF);
        int*   flg  = (int*)((char*)d_ws + XFL_OFF);
        u64*   XPq  = (u64*)((char*)d_ws + XXP_OFF);

        xprep_pack<<<dim3((A2_DW + WXA_DW + GROW + 255) / 256), dim3(256), 0, stream>>>(
            Wfi, Wfh, Wii, Wih, Wci, Wch, Woi, Woh,
            bfi, bfh, bii, bih, bci, bch, boi, boh, A2, WXA, bsum);
        xprep_hb<<<dim3(128), dim3(256), 0, stream>>>(h0, hbb, flg);
        xproj<<<dim3(TBN / 128), dim3(512), 0, stream>>>(x, WXA, bsum, XPq);
        lstm_rec<<<dim3(NWG), dim3(512), 0, stream>>>(c0, A2, hbb, flg, XPq, (float*)d_out);
    } else {
        u32* A     = (u32*)d_ws;
        u16* hbb   = (u16*)((char*)d_ws + HB_OFF);
        int* flags = (int*)((char*)d_ws + FL_OFF);
        prep_A<<<dim3(A_DWORDS / 256), dim3(256), 0, stream>>>(
            Wfi, Wfh, Wii, Wih, Wci, Wch, Woi, Woh, A);
        prep_misc<<<dim3(128), dim3(256), 0, stream>>>(h0, hbb, flags);
        lstm_mfma<<<dim3(32), dim3(512), 0, stream>>>(
            x, c0, bfi, bfh, bii, bih, bci, bch, boi, boh,
            A, hbb, flags, (float*)d_out);
    }
}